// Round 1
// baseline (440.668 us; speedup 1.0000x reference)
//
#include <hip/hip_runtime.h>

#define BT 32
#define CH 64
#define HS 56
#define WS 56
#define HH 28
#define WH 28
#define BSZ 16

// ---------------- filter constants (exact reference values) ----------------
namespace {
constexpr float ISQ2 = 0.70710678118654752440f;
constexpr float F_H0[13] = {-0.0017578125f, 0.0f, 0.022265625f, -0.046875f,
    -0.0482421875f, 0.296875f, 0.55546875f, 0.296875f, -0.0482421875f,
    -0.046875f, 0.022265625f, 0.0f, -0.0017578125f};
constexpr float F_H1[19] = {-7.0626e-05f, 0.0f, 0.00134189f, -0.00188341f,
    -0.0071566f, 0.023856f, 0.0556431f, -0.0516881f, -0.299758f, 0.559431f,
    -0.299758f, -0.0516881f, 0.0556431f, 0.023856f, -0.0071566f,
    -0.00188341f, 0.00134189f, 0.0f, -7.0626e-05f};
// G0 = alt(H1) (19 taps), G1 = alt(H0) (13 taps)
constexpr float F_G0[19] = {7.0626e-05f, 0.0f, -0.00134189f, -0.00188341f,
    0.0071566f, 0.023856f, -0.0556431f, -0.0516881f, 0.299758f, 0.559431f,
    0.299758f, -0.0516881f, -0.0556431f, 0.023856f, 0.0071566f,
    -0.00188341f, -0.00134189f, 0.0f, 7.0626e-05f};
constexpr float F_G1[13] = {-0.0017578125f, 0.0f, 0.022265625f, 0.046875f,
    -0.0482421875f, -0.296875f, 0.55546875f, -0.296875f, -0.0482421875f,
    0.046875f, 0.022265625f, 0.0f, -0.0017578125f};
}

// symmetric padding reflection, n = 56 (single reflection: taps <= 9)
__device__ __forceinline__ int symi(int k) {
    k = (k < 0) ? (-1 - k) : k;
    k = (k >= HS) ? (2 * HS - 1 - k) : k;
    return k;
}

// ------------------- K1: forward row filters: x -> lo, hi -------------------
__global__ __launch_bounds__(256) void k_fwd_rows(const float* __restrict__ x,
                                                  float* __restrict__ lo,
                                                  float* __restrict__ hi) {
    __shared__ float row[WS * CH];  // 14 KB
    int b = blockIdx.x / HS, h = blockIdx.x % HS;
    size_t base = ((size_t)(b * HS + h)) * WS * CH;
    for (int idx = threadIdx.x; idx < WS * CH; idx += 256) row[idx] = x[base + idx];
    __syncthreads();
    for (int idx = threadIdx.x; idx < WS * CH; idx += 256) {
        int w = idx >> 6, c = idx & 63;
        float aLo = 0.f, aHi = 0.f;
#pragma unroll
        for (int t = 0; t < 13; ++t) aLo += F_H0[t] * row[symi(w + t - 6) * CH + c];
#pragma unroll
        for (int t = 0; t < 19; ++t) aHi += F_H1[t] * row[symi(w + t - 9) * CH + c];
        lo[base + idx] = aLo;
        hi[base + idx] = aHi;
    }
}

// ---- K2a: lo path: column filters + q2c + channel mixing for s=0 (15) & 5 (165)
// also produces xl = ll * w_ll.
// yh layout: [b][s][i][wp][ri][c]
__global__ __launch_bounds__(256) void k_fwd_lo_mix(
    const float* __restrict__ lo, const float* __restrict__ w_ll,
    const float* __restrict__ w1, const float* __restrict__ w2,
    const float* __restrict__ b1, const float* __restrict__ b2,
    float* __restrict__ xl, float* __restrict__ yh) {
    __shared__ float loC[HS][2][CH];          // 28 KB
    __shared__ float sw1[2][BSZ][4][BSZ];     // [ri][d][nb][k]  8 KB
    __shared__ float sw2[2][BSZ][4][BSZ];     // 8 KB
    __shared__ float sbias[2][2][4][BSZ];     // [layer][ri][nb][k] 1 KB
    __shared__ float quad[4][CH];             // a,b,c,d of lh source
    __shared__ float sb[4][CH];               // s0r,s0i,s5r,s5i
    __shared__ float l1[4][CH];

    int b = blockIdx.x / WH, wp = blockIdx.x % WH;
    int w0 = 2 * wp, tid = threadIdx.x;

    for (int idx = tid; idx < HS * 128; idx += 256) {
        int h = idx >> 7, r = idx & 127;
        (&loC[0][0][0])[idx] = lo[((size_t)((b * HS + h) * WS + w0)) * CH + r];
    }
    for (int idx = tid; idx < 2048; idx += 256) {
        int ri = idx >> 10, rem = idx & 1023;
        int nb = rem >> 8, dd = (rem >> 4) & 15, k = idx & 15;
        sw1[ri][dd][nb][k] = w1[idx];
        sw2[ri][dd][nb][k] = w2[idx];
    }
    if (tid < 128) {
        (&sbias[0][0][0][0])[tid] = b1[tid];
        (&sbias[1][0][0][0])[tid] = b2[tid];
    }
    __syncthreads();

    int q = tid >> 6, c = tid & 63;
    int rp = q >> 1, jc = q & 1;
    int nb = c >> 4, k = c & 15;

    for (int i = 0; i < HH; ++i) {
        int h = 2 * i + rp;
        float vll = 0.f, vlh = 0.f;
#pragma unroll
        for (int t = 0; t < 13; ++t) vll += F_H0[t] * loC[symi(h + t - 6)][jc][c];
#pragma unroll
        for (int t = 0; t < 19; ++t) vlh += F_H1[t] * loC[symi(h + t - 9)][jc][c];
        int w = w0 + jc;
        xl[((size_t)((b * HS + h) * WS + w)) * CH + c] = vll * w_ll[(c * HS + h) * WS + w];
        quad[q][c] = vlh;
        __syncthreads();
        // q2c: s0: r=(a-d), i=(b+c); s5: r=(a+d), i=(b-c); all * 1/sqrt(2)
        {
            float a = quad[0][c], bb = quad[1][c], cv = quad[2][c], dv = quad[3][c];
            float v = (q == 0) ? (a - dv) : (q == 1) ? (bb + cv) : (q == 2) ? (a + dv) : (bb - cv);
            sb[q][c] = v * ISQ2;
        }
        __syncthreads();
        // layer 1 (complex, block-diag, relu): 2 subbands x 64 ch -> 128 threads
        if (tid < 128) {
            int p = tid >> 6;  // 0 -> s0, 1 -> s5
            float ar = sbias[0][0][nb][k], ai = sbias[0][1][nb][k];
#pragma unroll
            for (int dd = 0; dd < BSZ; ++dd) {
                float xr = sb[2 * p][nb * 16 + dd], xi = sb[2 * p + 1][nb * 16 + dd];
                float wr = sw1[0][dd][nb][k], wi = sw1[1][dd][nb][k];
                ar += xr * wr - xi * wi;
                ai += xr * wi + xi * wr;
            }
            l1[2 * p][c] = fmaxf(ar, 0.f);
            l1[2 * p + 1][c] = fmaxf(ai, 0.f);
        }
        __syncthreads();
        // layer 2 + store
        if (tid < 128) {
            int p = tid >> 6;
            float ar = sbias[1][0][nb][k], ai = sbias[1][1][nb][k];
#pragma unroll
            for (int dd = 0; dd < BSZ; ++dd) {
                float xr = l1[2 * p][nb * 16 + dd], xi = l1[2 * p + 1][nb * 16 + dd];
                float wr = sw2[0][dd][nb][k], wi = sw2[1][dd][nb][k];
                ar += xr * wr - xi * wi;
                ai += xr * wi + xi * wr;
            }
            int s = (p == 0) ? 0 : 5;
            size_t o = ((((size_t)(b * 6 + s) * HH + i) * WH + wp) * 2) * CH + c;
            yh[o] = ar;
            yh[o + CH] = ai;
        }
        __syncthreads();
    }
}

// ---- K2b: hi path: column filters + q2c + mixing for s=1(45),2(75),3(105),4(135)
__global__ __launch_bounds__(256) void k_fwd_hi_mix(
    const float* __restrict__ hi, const float* __restrict__ w1,
    const float* __restrict__ w2, const float* __restrict__ b1,
    const float* __restrict__ b2, float* __restrict__ yh) {
    __shared__ float hiC[HS][2][CH];       // 28 KB
    __shared__ float sw1[2][BSZ][4][BSZ];
    __shared__ float sw2[2][BSZ][4][BSZ];
    __shared__ float sbias[2][2][4][BSZ];
    __shared__ float quad[2][4][CH];       // [0]=hl source (H0), [1]=hh source (H1)
    __shared__ float sb[8][CH];            // s1r,s1i,s2r,s2i,s3r,s3i,s4r,s4i
    __shared__ float l1[8][CH];

    int b = blockIdx.x / WH, wp = blockIdx.x % WH;
    int w0 = 2 * wp, tid = threadIdx.x;

    for (int idx = tid; idx < HS * 128; idx += 256) {
        int h = idx >> 7, r = idx & 127;
        (&hiC[0][0][0])[idx] = hi[((size_t)((b * HS + h) * WS + w0)) * CH + r];
    }
    for (int idx = tid; idx < 2048; idx += 256) {
        int ri = idx >> 10, rem = idx & 1023;
        int nb = rem >> 8, dd = (rem >> 4) & 15, k = idx & 15;
        sw1[ri][dd][nb][k] = w1[idx];
        sw2[ri][dd][nb][k] = w2[idx];
    }
    if (tid < 128) {
        (&sbias[0][0][0][0])[tid] = b1[tid];
        (&sbias[1][0][0][0])[tid] = b2[tid];
    }
    __syncthreads();

    int q = tid >> 6, c = tid & 63;
    int rp = q >> 1, jc = q & 1;
    int nb = c >> 4, k = c & 15;

    for (int i = 0; i < HH; ++i) {
        int h = 2 * i + rp;
        float vhl = 0.f, vhh = 0.f;
#pragma unroll
        for (int t = 0; t < 13; ++t) vhl += F_H0[t] * hiC[symi(h + t - 6)][jc][c];
#pragma unroll
        for (int t = 0; t < 19; ++t) vhh += F_H1[t] * hiC[symi(h + t - 9)][jc][c];
        quad[0][q][c] = vhl;
        quad[1][q][c] = vhh;
        __syncthreads();
        // q2c: s2,s3 from hl; s1,s4 from hh. first: r=(a-d),i=(b+c); second: r=(a+d),i=(b-c)
        for (int idx = tid; idx < 512; idx += 256) {
            int j = idx >> 6, cc = idx & 63;
            int s = (j >> 1) + 1, ri = j & 1;
            int src = (s == 1 || s == 4) ? 1 : 0;
            bool second = (s >= 3);
            float a = quad[src][0][cc], bb = quad[src][1][cc];
            float cv = quad[src][2][cc], dv = quad[src][3][cc];
            float v = second ? (ri ? (bb - cv) : (a + dv)) : (ri ? (bb + cv) : (a - dv));
            sb[j][cc] = v * ISQ2;
        }
        __syncthreads();
        // layer 1: 4 subbands x 64 ch = 256 threads
        {
            int p = q;  // p = s-1
            float ar = sbias[0][0][nb][k], ai = sbias[0][1][nb][k];
#pragma unroll
            for (int dd = 0; dd < BSZ; ++dd) {
                float xr = sb[2 * p][nb * 16 + dd], xi = sb[2 * p + 1][nb * 16 + dd];
                float wr = sw1[0][dd][nb][k], wi = sw1[1][dd][nb][k];
                ar += xr * wr - xi * wi;
                ai += xr * wi + xi * wr;
            }
            l1[2 * p][c] = fmaxf(ar, 0.f);
            l1[2 * p + 1][c] = fmaxf(ai, 0.f);
        }
        __syncthreads();
        // layer 2 + store
        {
            int p = q;
            float ar = sbias[1][0][nb][k], ai = sbias[1][1][nb][k];
#pragma unroll
            for (int dd = 0; dd < BSZ; ++dd) {
                float xr = l1[2 * p][nb * 16 + dd], xi = l1[2 * p + 1][nb * 16 + dd];
                float wr = sw2[0][dd][nb][k], wi = sw2[1][dd][nb][k];
                ar += xr * wr - xi * wi;
                ai += xr * wi + xi * wr;
            }
            int s = p + 1;
            size_t o = ((((size_t)(b * 6 + s) * HH + i) * WH + wp) * 2) * CH + c;
            yh[o] = ar;
            yh[o + CH] = ai;
        }
        __syncthreads();
    }
}

// ---- K3: inverse column filters. mode 0: lo2 = G0(19)*xl + G1(13)*c2q(s0,s5)
//          mode 1: hi2 = G0(19)*c2q(s2,s3) + G1(13)*c2q(s1,s4)
__global__ __launch_bounds__(256) void k_inv_cols(const float* __restrict__ xl,
                                                  const float* __restrict__ yh,
                                                  float* __restrict__ outp,
                                                  int mode) {
    __shared__ float P19[HS][2][CH];  // 28 KB
    __shared__ float P13[HS][2][CH];  // 28 KB
    int b = blockIdx.x / WH, wp = blockIdx.x % WH;
    int w0 = 2 * wp, tid = threadIdx.x;

    if (mode == 0) {
        for (int idx = tid; idx < HS * 128; idx += 256) {
            int h = idx >> 7, r = idx & 127;
            (&P19[0][0][0])[idx] = xl[((size_t)((b * HS + h) * WS + w0)) * CH + r];
        }
        for (int idx = tid; idx < HH * CH; idx += 256) {
            int i = idx >> 6, cc = idx & 63;
            size_t o1 = ((((size_t)(b * 6 + 0) * HH + i) * WH + wp) * 2) * CH + cc;
            size_t o2 = ((((size_t)(b * 6 + 5) * HH + i) * WH + wp) * 2) * CH + cc;
            float r1 = yh[o1], i1 = yh[o1 + CH];
            float r2 = yh[o2], i2 = yh[o2 + CH];
            P13[2 * i][0][cc] = (r1 + r2) * ISQ2;
            P13[2 * i][1][cc] = (i1 + i2) * ISQ2;
            P13[2 * i + 1][0][cc] = (i1 - i2) * ISQ2;
            P13[2 * i + 1][1][cc] = (r2 - r1) * ISQ2;
        }
    } else {
        for (int idx = tid; idx < HH * CH; idx += 256) {
            int i = idx >> 6, cc = idx & 63;
            // P19 = c2q(s2, s3)
            size_t o1 = ((((size_t)(b * 6 + 2) * HH + i) * WH + wp) * 2) * CH + cc;
            size_t o2 = ((((size_t)(b * 6 + 3) * HH + i) * WH + wp) * 2) * CH + cc;
            float r1 = yh[o1], i1 = yh[o1 + CH];
            float r2 = yh[o2], i2 = yh[o2 + CH];
            P19[2 * i][0][cc] = (r1 + r2) * ISQ2;
            P19[2 * i][1][cc] = (i1 + i2) * ISQ2;
            P19[2 * i + 1][0][cc] = (i1 - i2) * ISQ2;
            P19[2 * i + 1][1][cc] = (r2 - r1) * ISQ2;
            // P13 = c2q(s1, s4)
            o1 = ((((size_t)(b * 6 + 1) * HH + i) * WH + wp) * 2) * CH + cc;
            o2 = ((((size_t)(b * 6 + 4) * HH + i) * WH + wp) * 2) * CH + cc;
            r1 = yh[o1]; i1 = yh[o1 + CH];
            r2 = yh[o2]; i2 = yh[o2 + CH];
            P13[2 * i][0][cc] = (r1 + r2) * ISQ2;
            P13[2 * i][1][cc] = (i1 + i2) * ISQ2;
            P13[2 * i + 1][0][cc] = (i1 - i2) * ISQ2;
            P13[2 * i + 1][1][cc] = (r2 - r1) * ISQ2;
        }
    }
    __syncthreads();
    for (int idx = tid; idx < HS * 128; idx += 256) {
        int h = idx >> 7, r = idx & 127;
        int jc = r >> 6, cc = r & 63;
        float acc = 0.f;
#pragma unroll
        for (int t = 0; t < 19; ++t) acc += F_G0[t] * P19[symi(h + t - 9)][jc][cc];
#pragma unroll
        for (int t = 0; t < 13; ++t) acc += F_G1[t] * P13[symi(h + t - 6)][jc][cc];
        outp[((size_t)((b * HS + h) * WS + w0)) * CH + r] = acc;
    }
}

// ------------------- K4: inverse row filters -> output -------------------
__global__ __launch_bounds__(256) void k_inv_rows(const float* __restrict__ lo2,
                                                  const float* __restrict__ hi2,
                                                  float* __restrict__ out) {
    __shared__ float rlo[WS * CH];  // 14 KB
    __shared__ float rhi[WS * CH];  // 14 KB
    int b = blockIdx.x / HS, h = blockIdx.x % HS;
    size_t base = ((size_t)(b * HS + h)) * WS * CH;
    for (int idx = threadIdx.x; idx < WS * CH; idx += 256) {
        rlo[idx] = lo2[base + idx];
        rhi[idx] = hi2[base + idx];
    }
    __syncthreads();
    for (int idx = threadIdx.x; idx < WS * CH; idx += 256) {
        int w = idx >> 6, c = idx & 63;
        float acc = 0.f;
#pragma unroll
        for (int t = 0; t < 19; ++t) acc += F_G0[t] * rlo[symi(w + t - 9) * CH + c];
#pragma unroll
        for (int t = 0; t < 13; ++t) acc += F_G1[t] * rhi[symi(w + t - 6) * CH + c];
        out[base + idx] = acc;
    }
}

extern "C" void kernel_launch(void* const* d_in, const int* in_sizes, int n_in,
                              void* d_out, int out_size, void* d_ws, size_t ws_size,
                              hipStream_t stream) {
    const float* x = (const float*)d_in[0];
    const float* w_ll = (const float*)d_in[1];
    const float* w1 = (const float*)d_in[2];
    const float* w2 = (const float*)d_in[3];
    const float* b1 = (const float*)d_in[4];
    const float* b2 = (const float*)d_in[5];
    float* out = (float*)d_out;

    const size_t plane = (size_t)BT * HS * WS * CH;  // 6,422,528 floats
    float* lo = (float*)d_ws;          // reused as lo2 in inverse
    float* hi = lo + plane;            // reused as hi2 in inverse
    float* xl = hi + plane;
    float* yh = xl + plane;            // [B][6][28][28][2][64] = 19,267,584 floats

    k_fwd_rows<<<BT * HS, 256, 0, stream>>>(x, lo, hi);
    k_fwd_lo_mix<<<BT * WH, 256, 0, stream>>>(lo, w_ll, w1, w2, b1, b2, xl, yh);
    k_fwd_hi_mix<<<BT * WH, 256, 0, stream>>>(hi, w1, w2, b1, b2, yh);
    k_inv_cols<<<BT * WH, 256, 0, stream>>>(xl, yh, lo, 0);   // lo2
    k_inv_cols<<<BT * WH, 256, 0, stream>>>(xl, yh, hi, 1);   // hi2
    k_inv_rows<<<BT * HS, 256, 0, stream>>>(lo, hi, out);
}

// Round 2
// 330.647 us; speedup vs baseline: 1.3327x; 1.3327x over previous
//
#include <hip/hip_runtime.h>

#define BT 32
#define CH 64
#define HS 56
#define WS 56
#define HH 28
#define WH 28

// ---------------- filter constants (exact reference values) ----------------
namespace {
constexpr float ISQ2 = 0.70710678118654752440f;
constexpr float F_H0[13] = {-0.0017578125f, 0.0f, 0.022265625f, -0.046875f,
    -0.0482421875f, 0.296875f, 0.55546875f, 0.296875f, -0.0482421875f,
    -0.046875f, 0.022265625f, 0.0f, -0.0017578125f};
constexpr float F_H1[19] = {-7.0626e-05f, 0.0f, 0.00134189f, -0.00188341f,
    -0.0071566f, 0.023856f, 0.0556431f, -0.0516881f, -0.299758f, 0.559431f,
    -0.299758f, -0.0516881f, 0.0556431f, 0.023856f, -0.0071566f,
    -0.00188341f, 0.00134189f, 0.0f, -7.0626e-05f};
constexpr float F_G0[19] = {7.0626e-05f, 0.0f, -0.00134189f, -0.00188341f,
    0.0071566f, 0.023856f, -0.0556431f, -0.0516881f, 0.299758f, 0.559431f,
    0.299758f, -0.0516881f, -0.0556431f, 0.023856f, 0.0071566f,
    -0.00188341f, -0.00134189f, 0.0f, 7.0626e-05f};
constexpr float F_G1[13] = {-0.0017578125f, 0.0f, 0.022265625f, 0.046875f,
    -0.0482421875f, -0.296875f, 0.55546875f, -0.296875f, -0.0482421875f,
    0.046875f, 0.022265625f, 0.0f, -0.0017578125f};
}

__device__ __forceinline__ int symi(int k) {
    k = (k < 0) ? (-1 - k) : k;
    k = (k >= HS) ? (2 * HS - 1 - k) : k;
    return k;
}

// ---- K0: transpose w_ll [c][h][w] -> wllT [h][w][c] (staged in d_out head)
__global__ __launch_bounds__(256) void k_wll_T(const float* __restrict__ wll,
                                               float* __restrict__ wllT) {
    __shared__ float tile[64][65];
    int pos0 = blockIdx.x * 64;
    int lp = threadIdx.x & 63, g = threadIdx.x >> 6;
#pragma unroll
    for (int r = 0; r < 16; ++r) {
        int cc = r * 4 + g;
        tile[cc][lp] = wll[(size_t)cc * (HS * WS) + pos0 + lp];
    }
    __syncthreads();
#pragma unroll
    for (int r = 0; r < 16; ++r) {
        int pl = r * 4 + g;
        wllT[(size_t)(pos0 + pl) * CH + lp] = tile[lp][pl];
    }
}

// ---- K1: forward row filters (sliding window, no LDS): x -> lo, hi
__global__ __launch_bounds__(256) void k_fwd_rows(const float* __restrict__ x,
                                                  float* __restrict__ lo,
                                                  float* __restrict__ hi) {
    int b = blockIdx.x / HS, h = blockIdx.x % HS;
    int strip = threadIdx.x >> 6, c = threadIdx.x & 63;
    const float* row = x + (size_t)(b * HS + h) * WS * CH + c;
    float* lop = lo + (size_t)(b * HS + h) * WS * CH + c;
    float* hip = hi + (size_t)(b * HS + h) * WS * CH + c;
    int w0s = strip * 14;
    float W[19];
#pragma unroll
    for (int t = 0; t < 19; ++t) W[t] = row[(size_t)symi(w0s - 9 + t) * CH];
#pragma unroll
    for (int k = 0; k < 14; ++k) {
        int w = w0s + k;
        float aLo = 0.f, aHi = 0.f;
#pragma unroll
        for (int t = 0; t < 13; ++t) aLo += F_H0[t] * W[3 + t];
#pragma unroll
        for (int t = 0; t < 19; ++t) aHi += F_H1[t] * W[t];
        lop[(size_t)w * CH] = aLo;
        hip[(size_t)w * CH] = aHi;
#pragma unroll
        for (int t = 0; t < 18; ++t) W[t] = W[t + 1];
        W[18] = row[(size_t)symi(w + 10) * CH];
    }
}

// ---- K2a: lo path: sliding-window column filters + batched q2c + mixing
// yh layout: [b][s][i][wp][ri][c]
__global__ __launch_bounds__(256) void k_lo_mix(
    const float* __restrict__ lo, const float* __restrict__ wllT,
    const float* __restrict__ w1, const float* __restrict__ w2,
    const float* __restrict__ b1, const float* __restrict__ b2,
    float* __restrict__ xl, float* __restrict__ yh) {
    __shared__ float sw1[2][16][4][16];   // [ri][d][nb][k] 8 KB
    __shared__ float sw2[2][16][4][16];   // 8 KB
    __shared__ float sbias[2][2][4][16];  // [layer][ri][nb][k] 1 KB
    __shared__ float qT[4][64][29];       // [j][c][i pad29] 29 KB

    int b = blockIdx.x / WH, wp = blockIdx.x % WH;
    int w0 = 2 * wp, tid = threadIdx.x;

    for (int idx = tid; idx < 2048; idx += 256) {
        int ri = idx >> 10, rem = idx & 1023;
        int nb = rem >> 8, dd = (rem >> 4) & 15, k = idx & 15;
        sw1[ri][dd][nb][k] = w1[idx];
        sw2[ri][dd][nb][k] = w2[idx];
    }
    if (tid < 128) {
        (&sbias[0][0][0][0])[tid] = b1[tid];
        (&sbias[1][0][0][0])[tid] = b2[tid];
    }

    int q = tid >> 6, c = tid & 63;
    int rp = q >> 1, jc = q & 1;
    const float* colbase = lo + (size_t)(b * HS) * WS * CH + (size_t)(w0 + jc) * CH + c;
    float W[19];
#pragma unroll
    for (int t = 0; t < 19; ++t) W[t] = colbase[(size_t)symi(rp - 9 + t) * WS * CH];

#pragma unroll
    for (int i = 0; i < 28; ++i) {
        int h = 2 * i + rp;
        float vll = 0.f, vlh = 0.f;
#pragma unroll
        for (int t = 0; t < 13; ++t) vll += F_H0[t] * W[3 + t];
#pragma unroll
        for (int t = 0; t < 19; ++t) vlh += F_H1[t] * W[t];
        xl[((size_t)(b * HS + h) * WS + (w0 + jc)) * CH + c] =
            vll * wllT[((size_t)h * WS + (w0 + jc)) * CH + c];
        qT[q][c][i] = vlh;
#pragma unroll
        for (int t = 0; t < 17; ++t) W[t] = W[t + 2];
        W[17] = colbase[(size_t)symi(h + 10) * WS * CH];
        W[18] = colbase[(size_t)symi(h + 11) * WS * CH];
    }
    __syncthreads();

    // in-place butterfly (q2c): j: 0=firstR 1=firstI 2=secondR 3=secondI
    {
        int cc = tid & 63, g = tid >> 6;
#pragma unroll
        for (int r = 0; r < 7; ++r) {
            int i = g * 7 + r;
            float a = qT[0][cc][i], bb = qT[1][cc][i];
            float cv = qT[2][cc][i], dv = qT[3][cc][i];
            qT[0][cc][i] = (a - dv) * ISQ2;
            qT[1][cc][i] = (bb + cv) * ISQ2;
            qT[2][cc][i] = (a + dv) * ISQ2;
            qT[3][cc][i] = (bb - cv) * ISQ2;
        }
    }
    __syncthreads();

    // mix: item = (p in 2, i in 28, nb in 4) = 224 work items
    if (tid < 224) {
        int nb = tid & 3, r = tid >> 2;
        int i = r % 28, p = r / 28;
        float l1r[16], l1i[16];
#pragma unroll
        for (int k = 0; k < 16; ++k) { l1r[k] = sbias[0][0][nb][k]; l1i[k] = sbias[0][1][nb][k]; }
#pragma unroll
        for (int d = 0; d < 16; ++d) {
            float xr = qT[2 * p][nb * 16 + d][i], xi = qT[2 * p + 1][nb * 16 + d][i];
#pragma unroll
            for (int k = 0; k < 16; ++k) {
                float wr = sw1[0][d][nb][k], wi = sw1[1][d][nb][k];
                l1r[k] += xr * wr - xi * wi;
                l1i[k] += xr * wi + xi * wr;
            }
        }
#pragma unroll
        for (int k = 0; k < 16; ++k) { l1r[k] = fmaxf(l1r[k], 0.f); l1i[k] = fmaxf(l1i[k], 0.f); }
        float or_[16], oi_[16];
#pragma unroll
        for (int k = 0; k < 16; ++k) { or_[k] = sbias[1][0][nb][k]; oi_[k] = sbias[1][1][nb][k]; }
#pragma unroll
        for (int d = 0; d < 16; ++d) {
            float xr = l1r[d], xi = l1i[d];
#pragma unroll
            for (int k = 0; k < 16; ++k) {
                float wr = sw2[0][d][nb][k], wi = sw2[1][d][nb][k];
                or_[k] += xr * wr - xi * wi;
                oi_[k] += xr * wi + xi * wr;
            }
        }
        int s = p ? 5 : 0;
        size_t o = ((((size_t)(b * 6 + s) * HH + i) * WH + wp) * 2) * CH + nb * 16;
#pragma unroll
        for (int k = 0; k < 16; ++k) { yh[o + k] = or_[k]; yh[o + CH + k] = oi_[k]; }
    }
}

// ---- K2b: hi path: same structure, 4 subbands, two half-rounds of i
__global__ __launch_bounds__(256) void k_hi_mix(
    const float* __restrict__ hi, const float* __restrict__ w1,
    const float* __restrict__ w2, const float* __restrict__ b1,
    const float* __restrict__ b2, float* __restrict__ yh) {
    __shared__ float sw1[2][16][4][16];
    __shared__ float sw2[2][16][4][16];
    __shared__ float sbias[2][2][4][16];
    __shared__ float qT[2][4][64][15];  // [src 0=hl 1=hh][j][c][ii pad15] 30 KB

    int b = blockIdx.x / WH, wp = blockIdx.x % WH;
    int w0 = 2 * wp, tid = threadIdx.x;

    for (int idx = tid; idx < 2048; idx += 256) {
        int ri = idx >> 10, rem = idx & 1023;
        int nb = rem >> 8, dd = (rem >> 4) & 15, k = idx & 15;
        sw1[ri][dd][nb][k] = w1[idx];
        sw2[ri][dd][nb][k] = w2[idx];
    }
    if (tid < 128) {
        (&sbias[0][0][0][0])[tid] = b1[tid];
        (&sbias[1][0][0][0])[tid] = b2[tid];
    }

    int q = tid >> 6, c = tid & 63;
    int rp = q >> 1, jc = q & 1;
    const float* colbase = hi + (size_t)(b * HS) * WS * CH + (size_t)(w0 + jc) * CH + c;
    float W[19];
#pragma unroll
    for (int t = 0; t < 19; ++t) W[t] = colbase[(size_t)symi(rp - 9 + t) * WS * CH];
    __syncthreads();

#pragma unroll
    for (int half = 0; half < 2; ++half) {
#pragma unroll
        for (int ii = 0; ii < 14; ++ii) {
            int i = half * 14 + ii, h = 2 * i + rp;
            float vhl = 0.f, vhh = 0.f;
#pragma unroll
            for (int t = 0; t < 13; ++t) vhl += F_H0[t] * W[3 + t];
#pragma unroll
            for (int t = 0; t < 19; ++t) vhh += F_H1[t] * W[t];
            qT[0][q][c][ii] = vhl;
            qT[1][q][c][ii] = vhh;
#pragma unroll
            for (int t = 0; t < 17; ++t) W[t] = W[t + 2];
            W[17] = colbase[(size_t)symi(h + 10) * WS * CH];
            W[18] = colbase[(size_t)symi(h + 11) * WS * CH];
        }
        __syncthreads();
        {
            int cc = tid & 63, g = tid >> 6;
#pragma unroll
            for (int r = 0; r < 7; ++r) {
                int slice = g * 7 + r;
                int src = slice / 14, ii = slice % 14;
                float a = qT[src][0][cc][ii], bb = qT[src][1][cc][ii];
                float cv = qT[src][2][cc][ii], dv = qT[src][3][cc][ii];
                qT[src][0][cc][ii] = (a - dv) * ISQ2;
                qT[src][1][cc][ii] = (bb + cv) * ISQ2;
                qT[src][2][cc][ii] = (a + dv) * ISQ2;
                qT[src][3][cc][ii] = (bb - cv) * ISQ2;
            }
        }
        __syncthreads();
        if (tid < 224) {
            int nb = tid & 3, r = tid >> 2;
            int ii = r % 14, sq = r / 14;            // sq 0..3 -> s = sq+1
            int src = (sq == 0 || sq == 3) ? 1 : 0;  // s1,s4 from hh
            int sec = (sq >= 2) ? 1 : 0;             // s3,s4 are "second"
            float l1r[16], l1i[16];
#pragma unroll
            for (int k = 0; k < 16; ++k) { l1r[k] = sbias[0][0][nb][k]; l1i[k] = sbias[0][1][nb][k]; }
#pragma unroll
            for (int d = 0; d < 16; ++d) {
                float xr = qT[src][2 * sec][nb * 16 + d][ii];
                float xi = qT[src][2 * sec + 1][nb * 16 + d][ii];
#pragma unroll
                for (int k = 0; k < 16; ++k) {
                    float wr = sw1[0][d][nb][k], wi = sw1[1][d][nb][k];
                    l1r[k] += xr * wr - xi * wi;
                    l1i[k] += xr * wi + xi * wr;
                }
            }
#pragma unroll
            for (int k = 0; k < 16; ++k) { l1r[k] = fmaxf(l1r[k], 0.f); l1i[k] = fmaxf(l1i[k], 0.f); }
            float or_[16], oi_[16];
#pragma unroll
            for (int k = 0; k < 16; ++k) { or_[k] = sbias[1][0][nb][k]; oi_[k] = sbias[1][1][nb][k]; }
#pragma unroll
            for (int d = 0; d < 16; ++d) {
                float xr = l1r[d], xi = l1i[d];
#pragma unroll
                for (int k = 0; k < 16; ++k) {
                    float wr = sw2[0][d][nb][k], wi = sw2[1][d][nb][k];
                    or_[k] += xr * wr - xi * wi;
                    oi_[k] += xr * wi + xi * wr;
                }
            }
            int i = half * 14 + ii, s = sq + 1;
            size_t o = ((((size_t)(b * 6 + s) * HH + i) * WH + wp) * 2) * CH + nb * 16;
#pragma unroll
            for (int k = 0; k < 16; ++k) { yh[o + k] = or_[k]; yh[o + CH + k] = oi_[k]; }
        }
        __syncthreads();
    }
}

// ---- K3: inverse column filters (sliding window, no LDS, c2q on the fly)
// mode 0: lo2 = G0*xl + G1*c2q(s0,s5);  mode 1: hi2 = G0*c2q(s2,s3) + G1*c2q(s1,s4)
__global__ __launch_bounds__(256) void k_inv_cols(const float* __restrict__ xl,
                                                  const float* __restrict__ yh,
                                                  float* __restrict__ lo2,
                                                  float* __restrict__ hi2) {
    int mode = blockIdx.y;
    int b = blockIdx.x / 14, wg = blockIdx.x % 14;
    int wl = threadIdx.x >> 6, c = threadIdx.x & 63;
    int w = wg * 4 + wl, wp = w >> 1, jw = w & 1;

    auto c2q = [&](int sa, int sb_, int r) -> float {
        int i = r >> 1;
        int sel = (r & 1) ^ jw;
        size_t oa = ((((size_t)(b * 6 + sa) * HH + i) * WH + wp) * 2 + sel) * CH + c;
        size_t ob = ((((size_t)(b * 6 + sb_) * HH + i) * WH + wp) * 2 + sel) * CH + c;
        float u = yh[oa], v = yh[ob];
        float val = ((r & 1) == 0) ? (u + v) : ((jw == 0) ? (u - v) : (v - u));
        return val * ISQ2;
    };
    auto ldA = [&](int r) -> float {
        if (mode == 0) return xl[((size_t)(b * HS + r) * WS + w) * CH + c];
        return c2q(2, 3, r);
    };
    auto ldB = [&](int r) -> float {
        return (mode == 0) ? c2q(0, 5, r) : c2q(1, 4, r);
    };
    float* outp = mode ? hi2 : lo2;

    float A[19], B[13];
#pragma unroll
    for (int t = 0; t < 19; ++t) A[t] = ldA(symi(t - 9));
#pragma unroll
    for (int t = 0; t < 13; ++t) B[t] = ldB(symi(t - 6));
#pragma unroll
    for (int h = 0; h < 56; ++h) {
        float acc = 0.f;
#pragma unroll
        for (int t = 0; t < 19; ++t) acc += F_G0[t] * A[t];
#pragma unroll
        for (int t = 0; t < 13; ++t) acc += F_G1[t] * B[t];
        outp[((size_t)(b * HS + h) * WS + w) * CH + c] = acc;
#pragma unroll
        for (int t = 0; t < 18; ++t) A[t] = A[t + 1];
#pragma unroll
        for (int t = 0; t < 12; ++t) B[t] = B[t + 1];
        A[18] = ldA(symi(h + 10));
        B[12] = ldB(symi(h + 7));
    }
}

// ---- K4: inverse row filters (sliding window, no LDS) -> out
__global__ __launch_bounds__(256) void k_inv_rows(const float* __restrict__ lo2,
                                                  const float* __restrict__ hi2,
                                                  float* __restrict__ out) {
    int b = blockIdx.x / HS, h = blockIdx.x % HS;
    int strip = threadIdx.x >> 6, c = threadIdx.x & 63;
    const float* rlo = lo2 + (size_t)(b * HS + h) * WS * CH + c;
    const float* rhi = hi2 + (size_t)(b * HS + h) * WS * CH + c;
    float* op = out + (size_t)(b * HS + h) * WS * CH + c;
    int w0s = strip * 14;
    float A[19], B[13];
#pragma unroll
    for (int t = 0; t < 19; ++t) A[t] = rlo[(size_t)symi(w0s - 9 + t) * CH];
#pragma unroll
    for (int t = 0; t < 13; ++t) B[t] = rhi[(size_t)symi(w0s - 6 + t) * CH];
#pragma unroll
    for (int k = 0; k < 14; ++k) {
        int w = w0s + k;
        float acc = 0.f;
#pragma unroll
        for (int t = 0; t < 19; ++t) acc += F_G0[t] * A[t];
#pragma unroll
        for (int t = 0; t < 13; ++t) acc += F_G1[t] * B[t];
        op[(size_t)w * CH] = acc;
#pragma unroll
        for (int t = 0; t < 18; ++t) A[t] = A[t + 1];
#pragma unroll
        for (int t = 0; t < 12; ++t) B[t] = B[t + 1];
        A[18] = rlo[(size_t)symi(w + 10) * CH];
        B[12] = rhi[(size_t)symi(w + 7) * CH];
    }
}

extern "C" void kernel_launch(void* const* d_in, const int* in_sizes, int n_in,
                              void* d_out, int out_size, void* d_ws, size_t ws_size,
                              hipStream_t stream) {
    const float* x = (const float*)d_in[0];
    const float* w_ll = (const float*)d_in[1];
    const float* w1 = (const float*)d_in[2];
    const float* w2 = (const float*)d_in[3];
    const float* b1 = (const float*)d_in[4];
    const float* b2 = (const float*)d_in[5];
    float* out = (float*)d_out;

    const size_t plane = (size_t)BT * HS * WS * CH;  // 6,422,528 floats
    float* lo = (float*)d_ws;   // reused as lo2
    float* hi = lo + plane;     // reused as hi2
    float* xl = hi + plane;
    float* yh = xl + plane;     // [B][6][28][28][2][64]
    float* wllT = out;          // staged in d_out head (overwritten by k_inv_rows)

    k_wll_T<<<49, 256, 0, stream>>>(w_ll, wllT);
    k_fwd_rows<<<BT * HS, 256, 0, stream>>>(x, lo, hi);
    k_lo_mix<<<BT * WH, 256, 0, stream>>>(lo, wllT, w1, w2, b1, b2, xl, yh);
    k_hi_mix<<<BT * WH, 256, 0, stream>>>(hi, w1, w2, b1, b2, yh);
    k_inv_cols<<<dim3(BT * 14, 2), 256, 0, stream>>>(xl, yh, lo, hi);
    k_inv_rows<<<BT * HS, 256, 0, stream>>>(lo, hi, out);
}